// Round 5
// baseline (267.818 us; speedup 1.0000x reference)
//
#include <hip/hip_runtime.h>
#include <stdint.h>

// ---- types ----
typedef unsigned short u16;
typedef __attribute__((ext_vector_type(4))) float f32x4;
typedef __attribute__((ext_vector_type(8))) __bf16 bf16x8;
typedef __attribute__((ext_vector_type(4))) unsigned int u32x4;

#define HWPX 4096   // H*W pixels
#define NMEM 8192   // T*H*W memory slots
#define CKD  64
#define VROWS 1024  // NOBJ*CV

__device__ __forceinline__ u16 f2bf(float x) {
    union { float f; unsigned u; } v; v.f = x;
    unsigned r = v.u + 0x7FFFu + ((v.u >> 16) & 1u);
    return (u16)(r >> 16);
}

// async global->LDS, 16B per lane; lds base wave-uniform (HW adds lane*16)
__device__ __forceinline__ void gld_lds16(const void* g, void* l) {
    __builtin_amdgcn_global_load_lds(
        (const __attribute__((address_space(1))) uint32_t*)g,
        (__attribute__((address_space(3))) uint32_t*)l, 16, 0, 0);
}

// ============================================================================
// FRAGMENT-ORDER LAYOUTS (proven r4). One 16B chunk = the 8 bf16 one lane
// feeds a 16x16x32 MFMA. chunk(lane l): row = base+(l&15), k = kk*32+(l>>4)*8+j.
//   Qf[pt 32][h 2][wm 2][mi 4][kk 2][l 64][8]   (1 MB)
//   Kf[nt 64][h 2][wn 2][ni 4][kk 2][l 64][8]   (2 MB)
//   Ptf[pb 32][kt 128][wn 2][ni 4][kk 2][l 64][8] (64 MB)
// ============================================================================

// -------- k1: prep (48 blocks) + mv->bf16 (512) + out-zero (256) ------------
__global__ void prep_aux(const float* __restrict__ qk, const float* __restrict__ qe,
                         const float* __restrict__ mk, const float* __restrict__ mv,
                         u16* __restrict__ Qf, float* __restrict__ bsq,
                         u16* __restrict__ Kf, u16* __restrict__ mvb,
                         float* __restrict__ outz) {
    const int bx = blockIdx.x;
    const int tid = threadIdx.x;
    if (bx < 16) {
        int p = bx * 256 + tid;   // 4096
        const int pt = p >> 7, wm = (p >> 6) & 1, mi = (p >> 4) & 3, l15 = p & 15;
        const size_t cb = ((((size_t)pt * 2 + 0) * 2 + wm) * 4 + mi) * 2;
        float acc = 0.f;
        #pragma unroll
        for (int cg = 0; cg < 8; ++cg) {
            const int kk = cg >> 2, quad = cg & 3;
            float kv[8], ev[8];
            #pragma unroll
            for (int j = 0; j < 8; ++j) {
                int c = cg * 8 + j;
                kv[j] = qk[c * HWPX + p];
                ev[j] = qe[c * HWPX + p];
                acc += ev[j] * kv[j] * kv[j];
            }
            unsigned w0[4], w1[4];
            #pragma unroll
            for (int jj = 0; jj < 4; ++jj) {
                w0[jj] = (unsigned)f2bf(kv[2*jj] * ev[2*jj]) |
                         ((unsigned)f2bf(kv[2*jj+1] * ev[2*jj+1]) << 16);
                w1[jj] = (unsigned)f2bf(ev[2*jj]) |
                         ((unsigned)f2bf(ev[2*jj+1]) << 16);
            }
            const size_t off = (size_t)quad * 128 + (size_t)l15 * 8;
            *(u32x4*)(Qf + (cb + kk) * 512 + off)      = (u32x4){w0[0], w0[1], w0[2], w0[3]};
            *(u32x4*)(Qf + (cb + 16 + kk) * 512 + off) = (u32x4){w1[0], w1[1], w1[2], w1[3]};
        }
        bsq[p] = acc;
        return;
    }
    if (bx < 48) {
        int n = (bx - 16) * 256 + tid;   // 8192
        const int nt = n >> 7, wn = (n >> 6) & 1, ni = (n >> 4) & 3, l15 = n & 15;
        const size_t cb = ((((size_t)nt * 2 + 0) * 2 + wn) * 4 + ni) * 2;
        #pragma unroll
        for (int cg = 0; cg < 8; ++cg) {
            const int kk = cg >> 2, quad = cg & 3;
            float m[8];
            #pragma unroll
            for (int j = 0; j < 8; ++j)
                m[j] = mk[(cg * 8 + j) * NMEM + n];
            unsigned w0[4], w1[4];
            #pragma unroll
            for (int jj = 0; jj < 4; ++jj) {
                w0[jj] = (unsigned)f2bf(2.f * m[2*jj]) |
                         ((unsigned)f2bf(2.f * m[2*jj+1]) << 16);
                w1[jj] = (unsigned)f2bf(-m[2*jj] * m[2*jj]) |
                         ((unsigned)f2bf(-m[2*jj+1] * m[2*jj+1]) << 16);
            }
            const size_t off = (size_t)quad * 128 + (size_t)l15 * 8;
            *(u32x4*)(Kf + (cb + kk) * 512 + off)      = (u32x4){w0[0], w0[1], w0[2], w0[3]};
            *(u32x4*)(Kf + (cb + 16 + kk) * 512 + off) = (u32x4){w1[0], w1[1], w1[2], w1[3]};
        }
        return;
    }
    if (bx < 560) {               // mv -> bf16 (2M float4s, 4096 per block)
        const int blk = bx - 48;
        #pragma unroll 4
        for (int it = 0; it < 16; ++it) {
            int i = blk * 4096 + it * 256 + tid;
            float4 v = ((const float4*)mv)[i];
            u16 o0 = f2bf(v.x), o1 = f2bf(v.y), o2 = f2bf(v.z), o3 = f2bf(v.w);
            unsigned lo = (unsigned)o0 | ((unsigned)o1 << 16);
            unsigned hi = (unsigned)o2 | ((unsigned)o3 << 16);
            ((uint2*)mvb)[i] = make_uint2(lo, hi);
        }
        return;
    }
    {                             // zero out (1M float4s, 4096 per block)
        const int blk = bx - 560;
        #pragma unroll 4
        for (int it = 0; it < 16; ++it) {
            int i = blk * 4096 + it * 256 + tid;
            ((float4*)outz)[i] = make_float4(0.f, 0.f, 0.f, 0.f);
        }
    }
}

// ---- gemm1 tiles: 128p x 128n, direct-reg operands (r4-proven), own kernel
__launch_bounds__(256, 2)
__global__ void gemm1_tiles(const u16* __restrict__ Qf, const u16* __restrict__ Kf,
                            const float* __restrict__ bsq, const float* __restrict__ ms,
                            u16* __restrict__ Pt, float* __restrict__ dpart) {
    __shared__ __align__(16) u16 smem[17408];   // Ps [128][136] only

    const int tile = blockIdx.x;    // 0..2047
    const int pb = tile & 31;       // p-tile (128 wide)
    const int nb = tile >> 5;       // n-tile (128 wide), 0..63
    const int p0 = pb * 128;
    const int n0 = nb * 128;

    const int tid  = threadIdx.x;
    const int l    = tid & 63;
    const int w    = tid >> 6;
    const int quad = l >> 4;
    const int l15  = l & 15;
    const int wm = w >> 1, wn = w & 1;   // wave tile: 64p x 64n

    f32x4 acc[4][4] = {};

    #pragma unroll
    for (int h = 0; h < 2; ++h) {
        bf16x8 a[4][2], b[4][2];
        const u16* qbase = Qf + ((((size_t)pb * 2 + h) * 2 + wm) * 4096) + (size_t)l * 8;
        const u16* kbase = Kf + ((((size_t)nb * 2 + h) * 2 + wn) * 4096) + (size_t)l * 8;
        #pragma unroll
        for (int mi = 0; mi < 4; ++mi) {
            a[mi][0] = *(const bf16x8*)(qbase + mi * 1024);
            a[mi][1] = *(const bf16x8*)(qbase + mi * 1024 + 512);
        }
        #pragma unroll
        for (int ni = 0; ni < 4; ++ni) {
            b[ni][0] = *(const bf16x8*)(kbase + ni * 1024);
            b[ni][1] = *(const bf16x8*)(kbase + ni * 1024 + 512);
        }
        #pragma unroll
        for (int kk = 0; kk < 2; ++kk)
            #pragma unroll
            for (int mi = 0; mi < 4; ++mi)
                #pragma unroll
                for (int ni = 0; ni < 4; ++ni)
                    acc[mi][ni] = __builtin_amdgcn_mfma_f32_16x16x32_bf16(a[mi][kk], b[ni][kk], acc[mi][ni], 0, 0, 0);
    }

    // per-lane epilogue constants
    float msv[4];
    #pragma unroll
    for (int ni = 0; ni < 4; ++ni)
        msv[ni] = ms[n0 + wn * 64 + ni * 16 + l15] * 0.125f;
    float bsv[4][4];
    #pragma unroll
    for (int mi = 0; mi < 4; ++mi)
        #pragma unroll
        for (int r = 0; r < 4; ++r)
            bsv[mi][r] = bsq[p0 + wm * 64 + mi * 16 + quad * 4 + r];

    u16* Ps = smem;              // [128][136] padded u16
    float rowsum[4][4] = {};
    #pragma unroll
    for (int mi = 0; mi < 4; ++mi) {
        #pragma unroll
        for (int ni = 0; ni < 4; ++ni) {
            f32x4 v = acc[mi][ni];
            int col = wn * 64 + ni * 16 + l15;
            #pragma unroll
            for (int r = 0; r < 4; ++r) {
                int rowl = wm * 64 + mi * 16 + quad * 4 + r;
                float pv = __expf((v[r] - bsv[mi][r]) * msv[ni]);
                rowsum[mi][r] += pv;
                Ps[rowl * 136 + col] = f2bf(pv);
            }
        }
    }
    // butterfly full-reduce over the 16-lane l15 group (16 sums/wave)
    #pragma unroll
    for (int mi = 0; mi < 4; ++mi)
        #pragma unroll
        for (int r = 0; r < 4; ++r) {
            float s = rowsum[mi][r];
            s += __shfl_xor(s, 1);
            s += __shfl_xor(s, 2);
            s += __shfl_xor(s, 4);
            s += __shfl_xor(s, 8);
            rowsum[mi][r] = s;
        }
    // exclusive-slot store: lane l15 owns (mi,r) = (l15>>2, l15&3); all 64 lanes
    {
        float myv = 0.f;
        #pragma unroll
        for (int mi = 0; mi < 4; ++mi)
            #pragma unroll
            for (int r = 0; r < 4; ++r)
                if (l15 == mi * 4 + r) myv = rowsum[mi][r];
        int slice = nb * 2 + wn;   // 0..127 (64-n spans)
        dpart[(size_t)slice * HWPX + p0 + wm * 64 + (l15 >> 2) * 16 + quad * 4 + (l15 & 3)] = myv;
    }
    __syncthreads();

    // Pt store in FRAGMENT ORDER: 32 chunks-of-1KB per block, wave-coalesced
    {
        const size_t dstBase = (size_t)pb * 1048576 + (size_t)nb * 16384;
        #pragma unroll
        for (int it = 0; it < 8; ++it) {
            const int combo = it * 4 + w;              // 0..31
            const int kt  = combo >> 4;                // local k-tile (64 n)
            const int wnq = (combo >> 3) & 1;
            const int niq = (combo >> 1) & 3;
            const int kkq = combo & 1;
            const u32x4* src = (const u32x4*)(Ps + (wnq * 64 + niq * 16 + l15) * 136
                                                 + kt * 64 + kkq * 32 + quad * 8);
            u32x4* dst = (u32x4*)(Pt + dstBase + kt * 8192 + wnq * 4096
                                     + niq * 1024 + kkq * 512 + l * 8);
            *dst = *src;
        }
    }
}

// ---- denom: 1/sum over the 128 dpart slices, once per pixel (16 blocks) ----
__global__ void denom_kernel(const float* __restrict__ dpart, float* __restrict__ dinvg) {
    const int p = blockIdx.x * 256 + threadIdx.x;   // 4096
    float s = 0.f;
    #pragma unroll 8
    for (int sl = 0; sl < 128; ++sl)
        s += dpart[(size_t)sl * HWPX + p];
    dinvg[p] = 1.0f / s;
}

// ---------------- GEMM2 v5: occupancy experiment --------------------------
// Structure = r4 (A via gld_lds, B direct-reg frag loads) but kz 4->8: grid
// 2048 = 8 blocks/CU AVAILABLE (was grid-limited to 4). LDS = As 16 KB only.
// launch_bounds(256,4) holds unified regs <=128 -> 4 waves/SIMD resident.
// dpart reduction hoisted to denom_kernel; epilogue just reads dinvg.
// Hypothesis under test: latency-bound w/ too few independent stall groups.
__launch_bounds__(256, 4)
__global__ void gemm2_kernel(const u16* __restrict__ Ab, const u16* __restrict__ Btf,
                             const float* __restrict__ dinvg, float* __restrict__ outacc) {
    __shared__ __align__(16) u16 As[128 * 64];   // 16 KB

    const int tid  = threadIdx.x;
    const int l    = tid & 63;
    const int w    = tid >> 6;
    const int quad = l >> 4;
    const int l15  = l & 15;
    const int wm = w >> 1, wn = w & 1;

    const int vb = blockIdx.x;      // 0..7  (XCD = lin&7 = vb: mvb slab L2-local)
    const int pb = blockIdx.y;      // 0..31
    const int kz = blockIdx.z;      // 0..7
    const int v0 = vb * 128;
    const int p0 = pb * 128;
    const int kbeg = kz * (NMEM / 8);   // 1024-wide K span, 16 iters

    const int rsub = tid >> 3;                      // 0..31
    const int csw  = (tid & 7) ^ (rsub & 7);        // swizzled source chunk

    const u16* bbase = Btf + (size_t)pb * 1048576 + (size_t)wn * 4096 + (size_t)l * 8;

    f32x4 acc[4][4] = {};

    for (int t = 0; t < 16; ++t) {
        const int k0 = kbeg + t * 64;
        const int kt = k0 >> 6;
        __syncthreads();
        #pragma unroll
        for (int rnd = 0; rnd < 4; ++rnd)
            gld_lds16(Ab + (size_t)(v0 + rnd * 32 + rsub) * NMEM + k0 + csw * 8,
                      As + rnd * 2048 + w * 512);
        bf16x8 b[4][2];
        {
            const u16* bk = bbase + (size_t)kt * 8192;
            #pragma unroll
            for (int ni = 0; ni < 4; ++ni) {
                b[ni][0] = *(const bf16x8*)(bk + ni * 1024);
                b[ni][1] = *(const bf16x8*)(bk + ni * 1024 + 512);
            }
        }
        __syncthreads();    // drains vmcnt: As staged AND b[] in regs
        #pragma unroll
        for (int kk = 0; kk < 2; ++kk) {
            bf16x8 a[4];
            #pragma unroll
            for (int mi = 0; mi < 4; ++mi) {
                int row = wm * 64 + mi * 16 + l15;
                a[mi] = *(const bf16x8*)(As + row * 64 + (((kk * 4 + quad) ^ (l15 & 7)) << 3));
            }
            #pragma unroll
            for (int mi = 0; mi < 4; ++mi)
                #pragma unroll
                for (int ni = 0; ni < 4; ++ni)
                    acc[mi][ni] = __builtin_amdgcn_mfma_f32_16x16x32_bf16(a[mi], b[ni][kk], acc[mi][ni], 0, 0, 0);
        }
    }

    // epilogue: divide by denom (precomputed) + atomic accumulate
    float dinv[4];
    #pragma unroll
    for (int ni = 0; ni < 4; ++ni)
        dinv[ni] = dinvg[p0 + wn * 64 + ni * 16 + l15];

    #pragma unroll
    for (int mi = 0; mi < 4; ++mi) {
        #pragma unroll
        for (int ni = 0; ni < 4; ++ni) {
            int col = p0 + wn * 64 + ni * 16 + l15;
            f32x4 v = acc[mi][ni];
            #pragma unroll
            for (int r = 0; r < 4; ++r) {
                int row = v0 + wm * 64 + mi * 16 + quad * 4 + r;
                atomicAdd(&outacc[(size_t)row * HWPX + col], v[r] * dinv[ni]);
            }
        }
    }
}

// ---------------- launch ----------------
extern "C" void kernel_launch(void* const* d_in, const int* in_sizes, int n_in,
                              void* d_out, int out_size, void* d_ws, size_t ws_size,
                              hipStream_t stream) {
    const float* qk = (const float*)d_in[0];  // (1,64,64,64)
    const float* qe = (const float*)d_in[1];  // (1,64,64,64)
    const float* mk = (const float*)d_in[2];  // (1,64,2,64,64)
    const float* ms = (const float*)d_in[3];  // (1,1,2,64,64)
    const float* mv = (const float*)d_in[4];  // (1,2,512,2,64,64)
    float* out = (float*)d_out;               // (1,2,512,64,64)

    char* ws = (char*)d_ws;
    u16*   Pt    = (u16*)ws;                               // 64 MB  frag-order Ptf
    u16*   mvb   = (u16*)(ws + ((size_t)64 << 20));        // 16 MB  [1024][8192] bf16
    u16*   Kf    = (u16*)(ws + ((size_t)80 << 20));        // 2 MB   frag-order Kf
    u16*   Qf    = (u16*)(ws + ((size_t)82 << 20));        // 1 MB   frag-order Qf
    float* bsq   = (float*)(ws + ((size_t)83 << 20));      // 16 KB
    float* dpart = (float*)(ws + ((size_t)83 << 20) + 65536);           // 2 MB
    float* dinvg = (float*)(ws + ((size_t)83 << 20) + 65536 + (2 << 20)); // 16 KB

    // prep (48) + mv-convert (512) + out-zero (256)
    prep_aux<<<816, 256, 0, stream>>>(qk, qe, mk, mv, Qf, bsq, Kf, mvb, out);

    // 2048 gemm1 tiles (128p x 128n)
    gemm1_tiles<<<2048, 256, 0, stream>>>(Qf, Kf, bsq, ms, Pt, dpart);

    // 4096-pixel denom table
    denom_kernel<<<16, 256, 0, stream>>>(dpart, dinvg);

    // 2048 blocks = vb(8, =XCD) x pb(32) x kz(8); 8 blocks/CU available
    dim3 g2(8, 32, 8);
    gemm2_kernel<<<g2, 256, 0, stream>>>(mvb, Pt, dinvg, out);
}

// Round 7
// 219.090 us; speedup vs baseline: 1.2224x; 1.2224x over previous
//
#include <hip/hip_runtime.h>
#include <stdint.h>

// ---- types ----
typedef unsigned short u16;
typedef __attribute__((ext_vector_type(4))) float f32x4;
typedef __attribute__((ext_vector_type(8))) __bf16 bf16x8;
typedef __attribute__((ext_vector_type(4))) unsigned int u32x4;

#define HWPX 4096   // H*W pixels
#define NMEM 8192   // T*H*W memory slots
#define CKD  64
#define VROWS 1024  // NOBJ*CV

__device__ __forceinline__ u16 f2bf(float x) {
    union { float f; unsigned u; } v; v.f = x;
    unsigned r = v.u + 0x7FFFu + ((v.u >> 16) & 1u);
    return (u16)(r >> 16);
}

// async global->LDS, 16B per lane; lds base wave-uniform (HW adds lane*16)
__device__ __forceinline__ void gld_lds16(const void* g, void* l) {
    __builtin_amdgcn_global_load_lds(
        (const __attribute__((address_space(1))) uint32_t*)g,
        (__attribute__((address_space(3))) uint32_t*)l, 16, 0, 0);
}

// ============================================================================
// FRAGMENT-ORDER LAYOUTS (proven r4). One 16B chunk = the 8 bf16 one lane
// feeds a 16x16x32 MFMA. chunk(lane l): row = base+(l&15), k = kk*32+(l>>4)*8+j.
//   Qf[pt 32][h 2][wm 2][mi 4][kk 2][l 64][8]   (1 MB)
//   Kf[nt 64][h 2][wn 2][ni 4][kk 2][l 64][8]   (2 MB)
//   Ptf[pb 32][kt 128][wn 2][ni 4][kk 2][l 64][8] (64 MB)
// ============================================================================

// -------- k1: prep (48 blocks) + mv->bf16 (512). out-zero DELETED (kz=1) ----
__global__ void prep_aux(const float* __restrict__ qk, const float* __restrict__ qe,
                         const float* __restrict__ mk, const float* __restrict__ mv,
                         u16* __restrict__ Qf, float* __restrict__ bsq,
                         u16* __restrict__ Kf, u16* __restrict__ mvb) {
    const int bx = blockIdx.x;
    const int tid = threadIdx.x;
    if (bx < 16) {
        int p = bx * 256 + tid;   // 4096
        const int pt = p >> 7, wm = (p >> 6) & 1, mi = (p >> 4) & 3, l15 = p & 15;
        const size_t cb = ((((size_t)pt * 2 + 0) * 2 + wm) * 4 + mi) * 2;
        float acc = 0.f;
        #pragma unroll
        for (int cg = 0; cg < 8; ++cg) {
            const int kk = cg >> 2, quad = cg & 3;
            float kv[8], ev[8];
            #pragma unroll
            for (int j = 0; j < 8; ++j) {
                int c = cg * 8 + j;
                kv[j] = qk[c * HWPX + p];
                ev[j] = qe[c * HWPX + p];
                acc += ev[j] * kv[j] * kv[j];
            }
            unsigned w0[4], w1[4];
            #pragma unroll
            for (int jj = 0; jj < 4; ++jj) {
                w0[jj] = (unsigned)f2bf(kv[2*jj] * ev[2*jj]) |
                         ((unsigned)f2bf(kv[2*jj+1] * ev[2*jj+1]) << 16);
                w1[jj] = (unsigned)f2bf(ev[2*jj]) |
                         ((unsigned)f2bf(ev[2*jj+1]) << 16);
            }
            const size_t off = (size_t)quad * 128 + (size_t)l15 * 8;
            *(u32x4*)(Qf + (cb + kk) * 512 + off)      = (u32x4){w0[0], w0[1], w0[2], w0[3]};
            *(u32x4*)(Qf + (cb + 16 + kk) * 512 + off) = (u32x4){w1[0], w1[1], w1[2], w1[3]};
        }
        bsq[p] = acc;
        return;
    }
    if (bx < 48) {
        int n = (bx - 16) * 256 + tid;   // 8192
        const int nt = n >> 7, wn = (n >> 6) & 1, ni = (n >> 4) & 3, l15 = n & 15;
        const size_t cb = ((((size_t)nt * 2 + 0) * 2 + wn) * 4 + ni) * 2;
        #pragma unroll
        for (int cg = 0; cg < 8; ++cg) {
            const int kk = cg >> 2, quad = cg & 3;
            float m[8];
            #pragma unroll
            for (int j = 0; j < 8; ++j)
                m[j] = mk[(cg * 8 + j) * NMEM + n];
            unsigned w0[4], w1[4];
            #pragma unroll
            for (int jj = 0; jj < 4; ++jj) {
                w0[jj] = (unsigned)f2bf(2.f * m[2*jj]) |
                         ((unsigned)f2bf(2.f * m[2*jj+1]) << 16);
                w1[jj] = (unsigned)f2bf(-m[2*jj] * m[2*jj]) |
                         ((unsigned)f2bf(-m[2*jj+1] * m[2*jj+1]) << 16);
            }
            const size_t off = (size_t)quad * 128 + (size_t)l15 * 8;
            *(u32x4*)(Kf + (cb + kk) * 512 + off)      = (u32x4){w0[0], w0[1], w0[2], w0[3]};
            *(u32x4*)(Kf + (cb + 16 + kk) * 512 + off) = (u32x4){w1[0], w1[1], w1[2], w1[3]};
        }
        return;
    }
    {                             // mv -> bf16 (2M float4s, 4096 per block)
        const int blk = bx - 48;
        #pragma unroll 4
        for (int it = 0; it < 16; ++it) {
            int i = blk * 4096 + it * 256 + tid;
            float4 v = ((const float4*)mv)[i];
            u16 o0 = f2bf(v.x), o1 = f2bf(v.y), o2 = f2bf(v.z), o3 = f2bf(v.w);
            unsigned lo = (unsigned)o0 | ((unsigned)o1 << 16);
            unsigned hi = (unsigned)o2 | ((unsigned)o3 << 16);
            ((uint2*)mvb)[i] = make_uint2(lo, hi);
        }
    }
}

// ---- gemm1 tiles: 128p x 128n, direct-reg operands (r4-proven), unchanged
__launch_bounds__(256, 2)
__global__ void gemm1_tiles(const u16* __restrict__ Qf, const u16* __restrict__ Kf,
                            const float* __restrict__ bsq, const float* __restrict__ ms,
                            u16* __restrict__ Pt, float* __restrict__ dpart) {
    __shared__ __align__(16) u16 smem[17408];   // Ps [128][136] only

    const int tile = blockIdx.x;    // 0..2047
    const int pb = tile & 31;       // p-tile (128 wide)
    const int nb = tile >> 5;       // n-tile (128 wide), 0..63
    const int p0 = pb * 128;
    const int n0 = nb * 128;

    const int tid  = threadIdx.x;
    const int l    = tid & 63;
    const int w    = tid >> 6;
    const int quad = l >> 4;
    const int l15  = l & 15;
    const int wm = w >> 1, wn = w & 1;   // wave tile: 64p x 64n

    f32x4 acc[4][4] = {};

    #pragma unroll
    for (int h = 0; h < 2; ++h) {
        bf16x8 a[4][2], b[4][2];
        const u16* qbase = Qf + ((((size_t)pb * 2 + h) * 2 + wm) * 4096) + (size_t)l * 8;
        const u16* kbase = Kf + ((((size_t)nb * 2 + h) * 2 + wn) * 4096) + (size_t)l * 8;
        #pragma unroll
        for (int mi = 0; mi < 4; ++mi) {
            a[mi][0] = *(const bf16x8*)(qbase + mi * 1024);
            a[mi][1] = *(const bf16x8*)(qbase + mi * 1024 + 512);
        }
        #pragma unroll
        for (int ni = 0; ni < 4; ++ni) {
            b[ni][0] = *(const bf16x8*)(kbase + ni * 1024);
            b[ni][1] = *(const bf16x8*)(kbase + ni * 1024 + 512);
        }
        #pragma unroll
        for (int kk = 0; kk < 2; ++kk)
            #pragma unroll
            for (int mi = 0; mi < 4; ++mi)
                #pragma unroll
                for (int ni = 0; ni < 4; ++ni)
                    acc[mi][ni] = __builtin_amdgcn_mfma_f32_16x16x32_bf16(a[mi][kk], b[ni][kk], acc[mi][ni], 0, 0, 0);
    }

    // per-lane epilogue constants
    float msv[4];
    #pragma unroll
    for (int ni = 0; ni < 4; ++ni)
        msv[ni] = ms[n0 + wn * 64 + ni * 16 + l15] * 0.125f;
    float bsv[4][4];
    #pragma unroll
    for (int mi = 0; mi < 4; ++mi)
        #pragma unroll
        for (int r = 0; r < 4; ++r)
            bsv[mi][r] = bsq[p0 + wm * 64 + mi * 16 + quad * 4 + r];

    u16* Ps = smem;              // [128][136] padded u16
    float rowsum[4][4] = {};
    #pragma unroll
    for (int mi = 0; mi < 4; ++mi) {
        #pragma unroll
        for (int ni = 0; ni < 4; ++ni) {
            f32x4 v = acc[mi][ni];
            int col = wn * 64 + ni * 16 + l15;
            #pragma unroll
            for (int r = 0; r < 4; ++r) {
                int rowl = wm * 64 + mi * 16 + quad * 4 + r;
                float pv = __expf((v[r] - bsv[mi][r]) * msv[ni]);
                rowsum[mi][r] += pv;
                Ps[rowl * 136 + col] = f2bf(pv);
            }
        }
    }
    // butterfly full-reduce over the 16-lane l15 group (16 sums/wave)
    #pragma unroll
    for (int mi = 0; mi < 4; ++mi)
        #pragma unroll
        for (int r = 0; r < 4; ++r) {
            float s = rowsum[mi][r];
            s += __shfl_xor(s, 1);
            s += __shfl_xor(s, 2);
            s += __shfl_xor(s, 4);
            s += __shfl_xor(s, 8);
            rowsum[mi][r] = s;
        }
    // exclusive-slot store: lane l15 owns (mi,r) = (l15>>2, l15&3); all 64 lanes
    {
        float myv = 0.f;
        #pragma unroll
        for (int mi = 0; mi < 4; ++mi)
            #pragma unroll
            for (int r = 0; r < 4; ++r)
                if (l15 == mi * 4 + r) myv = rowsum[mi][r];
        int slice = nb * 2 + wn;   // 0..127 (64-n spans)
        dpart[(size_t)slice * HWPX + p0 + wm * 64 + (l15 >> 2) * 16 + quad * 4 + (l15 & 3)] = myv;
    }
    __syncthreads();

    // Pt store in FRAGMENT ORDER: 32 chunks-of-1KB per block, wave-coalesced
    {
        const size_t dstBase = (size_t)pb * 1048576 + (size_t)nb * 16384;
        #pragma unroll
        for (int it = 0; it < 8; ++it) {
            const int combo = it * 4 + w;              // 0..31
            const int kt  = combo >> 4;                // local k-tile (64 n)
            const int wnq = (combo >> 3) & 1;
            const int niq = (combo >> 1) & 3;
            const int kkq = combo & 1;
            const u32x4* src = (const u32x4*)(Ps + (wnq * 64 + niq * 16 + l15) * 136
                                                 + kt * 64 + kkq * 32 + quad * 8);
            u32x4* dst = (u32x4*)(Pt + dstBase + kt * 8192 + wnq * 4096
                                     + niq * 1024 + kkq * 512 + l * 8);
            *dst = *src;
        }
    }
}

// ---- denom: 1/sum over the 128 dpart slices, once per pixel (16 blocks) ----
__global__ void denom_kernel(const float* __restrict__ dpart, float* __restrict__ dinvg) {
    const int p = blockIdx.x * 256 + threadIdx.x;   // 4096
    float s = 0.f;
    #pragma unroll 8
    for (int sl = 0; sl < 128; ++sl)
        s += dpart[(size_t)sl * HWPX + p];
    dinvg[p] = 1.0f / s;
}

// ---------------- GEMM2 v6: no-split-K, counted-vmcnt, no drains ----------
// r5 proved: time = max(MFMA 27.5us, traffic/2.9TB/s, latency-exposure), and
// ~12 waves/CU suffice to hide latency IF vmcnt never drains. Design:
//  - kz=1: atomics -> plain stores (WRITE 64->16MB), no out-zero, no out RMW.
//  - BM=64 x BN=128, grid 512 = vb16 x pb32; XCD = pb_lo (r0-proven locality:
//    Pt slab fetched once per XCD).
//  - A (mvb) via gld_lds, 3-buffer ring (8KB each), staged depth-2 ahead.
//  - B (Ptf frag-order) direct-to-reg, same iter.
//  - ONE vmcnt(2) + ONE barrier per iter; never vmcnt(0) mid-loop.
//    Issue order B-loads THEN A-stage is pinned by sched_barrier(0) so the
//    "2 newest outstanding = A-stage" count is guaranteed (r6 hardening).
__launch_bounds__(256, 4)
__global__ void gemm2_kernel(const u16* __restrict__ Ab, const u16* __restrict__ Btf,
                             const float* __restrict__ dinvg, float* __restrict__ outacc) {
    __shared__ __align__(16) u16 As3[3 * 4096];   // 24 KB: 3 A-buffers [64][64]

    const int tid  = threadIdx.x;
    const int l    = tid & 63;
    const int w    = tid >> 6;      // 0..3
    const int quad = l >> 4;
    const int l15  = l & 15;
    const int wm = w >> 1, wn = w & 1;   // wave tile: 32v x 64p

    const int lin = blockIdx.x;     // 512
    const int pb  = (lin & 7) | (((lin >> 7) & 3) << 3);   // XCD = lin&7 = pb_lo
    const int vb  = (lin >> 3) & 15;
    const int v0 = vb * 64;
    const int p0 = pb * 128;
    const int NT = NMEM / 64;       // 128 K-tiles

    const int rsub = tid >> 3;                      // 0..31
    const int csw  = (tid & 7) ^ (rsub & 7);        // swizzled source chunk

    const u16* bbase = Btf + (size_t)pb * 1048576 + (size_t)wn * 4096 + (size_t)l * 8;

    u16* pR = As3;              // A(t)   read
    u16* pN = As3 + 4096;       // A(t+1) ready/in-flight
    u16* pS = As3 + 8192;       // A(t+2) stage target

    #define STAGE_A(k0g, dst)                                                    \
        { _Pragma("unroll")                                                      \
          for (int rnd = 0; rnd < 2; ++rnd)                                      \
              gld_lds16(Ab + (size_t)(v0 + rnd * 32 + rsub) * NMEM + (k0g) + csw * 8, \
                        (dst) + rnd * 2048 + w * 512); }

    f32x4 acc[2][4] = {};

    // prologue: A(0)->pR, A(1)->pN; wait A(0) (A(1)'s 2 loads stay in flight)
    STAGE_A(0, pR)
    STAGE_A(64, pN)
    asm volatile("s_waitcnt vmcnt(2)" ::: "memory");
    __builtin_amdgcn_s_barrier();
    __builtin_amdgcn_sched_barrier(0);

    for (int t = 0; t < NT; ++t) {
        const bool st = (t + 2 < NT);
        // b(t): 8 direct frag loads (Ptf) -- must ISSUE BEFORE the A-stage
        bf16x8 b[4][2];
        const u16* bk = bbase + (size_t)t * 8192;
        #pragma unroll
        for (int ni = 0; ni < 4; ++ni) {
            b[ni][0] = *(const bf16x8*)(bk + ni * 1024);
            b[ni][1] = *(const bf16x8*)(bk + ni * 1024 + 512);
        }
        __builtin_amdgcn_sched_barrier(0);   // pin: b-loads before A-stage
        // stage A(t+2)
        if (st) STAGE_A((t + 2) * 64, pS)
        // a(t) from pR
        bf16x8 a[2][2];
        #pragma unroll
        for (int kk = 0; kk < 2; ++kk)
            #pragma unroll
            for (int mi = 0; mi < 2; ++mi) {
                int row = wm * 32 + mi * 16 + l15;
                a[mi][kk] = *(const bf16x8*)(pR + row * 64 + (((kk * 4 + quad) ^ (l15 & 7)) << 3));
            }
        __builtin_amdgcn_sched_barrier(0);
        if (st) { asm volatile("s_waitcnt vmcnt(2)" ::: "memory"); }   // b(t)+A(t+1) done
        else    { asm volatile("s_waitcnt vmcnt(0)" ::: "memory"); }
        asm volatile("s_waitcnt lgkmcnt(0)" ::: "memory");
        __builtin_amdgcn_sched_barrier(0);
        __builtin_amdgcn_s_setprio(1);
        #pragma unroll
        for (int kk = 0; kk < 2; ++kk)
            #pragma unroll
            for (int mi = 0; mi < 2; ++mi)
                #pragma unroll
                for (int ni = 0; ni < 4; ++ni)
                    acc[mi][ni] = __builtin_amdgcn_mfma_f32_16x16x32_bf16(a[mi][kk], b[ni][kk], acc[mi][ni], 0, 0, 0);
        __builtin_amdgcn_s_setprio(0);
        __builtin_amdgcn_s_barrier();
        __builtin_amdgcn_sched_barrier(0);
        u16* tmp = pR; pR = pN; pN = pS; pS = tmp;
    }
    #undef STAGE_A

    // epilogue: scale by 1/denom and plain-store (exclusive tile, kz=1)
    float dinv[4];
    #pragma unroll
    for (int ni = 0; ni < 4; ++ni)
        dinv[ni] = dinvg[p0 + wn * 64 + ni * 16 + l15];

    #pragma unroll
    for (int mi = 0; mi < 2; ++mi) {
        #pragma unroll
        for (int ni = 0; ni < 4; ++ni) {
            int col = p0 + wn * 64 + ni * 16 + l15;
            f32x4 v = acc[mi][ni];
            #pragma unroll
            for (int r = 0; r < 4; ++r) {
                int row = v0 + wm * 32 + mi * 16 + quad * 4 + r;
                outacc[(size_t)row * HWPX + col] = v[r] * dinv[ni];
            }
        }
    }
}

// ---------------- launch ----------------
extern "C" void kernel_launch(void* const* d_in, const int* in_sizes, int n_in,
                              void* d_out, int out_size, void* d_ws, size_t ws_size,
                              hipStream_t stream) {
    const float* qk = (const float*)d_in[0];  // (1,64,64,64)
    const float* qe = (const float*)d_in[1];  // (1,64,64,64)
    const float* mk = (const float*)d_in[2];  // (1,64,2,64,64)
    const float* ms = (const float*)d_in[3];  // (1,1,2,64,64)
    const float* mv = (const float*)d_in[4];  // (1,2,512,2,64,64)
    float* out = (float*)d_out;               // (1,2,512,64,64)

    char* ws = (char*)d_ws;
    u16*   Pt    = (u16*)ws;                               // 64 MB  frag-order Ptf
    u16*   mvb   = (u16*)(ws + ((size_t)64 << 20));        // 16 MB  [1024][8192] bf16
    u16*   Kf    = (u16*)(ws + ((size_t)80 << 20));        // 2 MB   frag-order Kf
    u16*   Qf    = (u16*)(ws + ((size_t)82 << 20));        // 1 MB   frag-order Qf
    float* bsq   = (float*)(ws + ((size_t)83 << 20));      // 16 KB
    float* dpart = (float*)(ws + ((size_t)83 << 20) + 65536);           // 2 MB
    float* dinvg = (float*)(ws + ((size_t)83 << 20) + 65536 + (2 << 20)); // 16 KB

    // prep (48) + mv-convert (512); no out-zero needed (kz=1 plain stores)
    prep_aux<<<560, 256, 0, stream>>>(qk, qe, mk, mv, Qf, bsq, Kf, mvb);

    // 2048 gemm1 tiles (128p x 128n)
    gemm1_tiles<<<2048, 256, 0, stream>>>(Qf, Kf, bsq, ms, Pt, dpart);

    // 4096-pixel denom table
    denom_kernel<<<16, 256, 0, stream>>>(dpart, dinvg);

    // 512 blocks = vb16 x pb32, XCD = pb_lo; 256 threads; 4 blocks/CU
    gemm2_kernel<<<512, 256, 0, stream>>>(mvb, Pt, dinvg, out);
}